// Round 1
// baseline (416.214 us; speedup 1.0000x reference)
//
#include <hip/hip_runtime.h>
#include <hip/hip_bf16.h>

// GatedNorm: out = xn * sigmoid(W_up @ silu(W_down @ xn)), xn = rmsnorm(x)
// B=4, S=4096, DIM=4096, R=128. All fp32 in/out. Fused single kernel:
//  - 16 tokens/block, x staged to LDS as bf16 (XOR-swizzled), sumsq on the fly
//  - down-proj via mfma_f32_16x16x32_bf16 (normalization deferred: scale h_pre)
//  - up-proj computed transposed so epilogue stores are vectorized float4
//  - weights pre-converted to bf16 in d_ws by a prep kernel (fallback: fp32 loads)

#define DIMX  4096
#define RLOW  128
#define BT    16
#define KC    512
#define NCH   (DIMX / KC)   // 8
#define THREADS 256

typedef __attribute__((ext_vector_type(8))) short  bf16x8;
typedef __attribute__((ext_vector_type(4))) float  f32x4;

// LDS layout (dynamic):
//   x_lds : [BT][DIMX] bf16, row stride 8192 B, swizzle byte ^= ((row&7)<<4)
//   h_lds : [BT][HP] bf16 (HP=136 padded to avoid bank conflicts)
//   invr  : [BT] float
#define X_BYTES   (BT * DIMX * 2)          // 131072
#define HP        136
#define H_OFF     X_BYTES
#define INV_OFF   (H_OFF + BT * HP * 2)    // +4352
#define LDS_BYTES (INV_OFF + BT * 4)

__device__ __forceinline__ unsigned short f2bf(float f) {
    unsigned int u = __float_as_uint(f);
    u = u + 0x7fffu + ((u >> 16) & 1u);     // RNE
    return (unsigned short)(u >> 16);
}
__device__ __forceinline__ float bf2f(unsigned short s) {
    return __uint_as_float((unsigned int)s << 16);
}
__device__ __forceinline__ float sigm(float v) { return 1.0f / (1.0f + __expf(-v)); }

// 8 contiguous bf16 weight elements, either from pre-converted bf16 or fp32+cvt
template<bool PREP>
__device__ __forceinline__ bf16x8 load_w8(const unsigned short* __restrict__ wbf,
                                          const float* __restrict__ wf, long off) {
    if constexpr (PREP) {
        return *(const bf16x8*)(wbf + off);
    } else {
        float4 a = *(const float4*)(wf + off);
        float4 b = *(const float4*)(wf + off + 4);
        bf16x8 r;
        r[0] = (short)f2bf(a.x); r[1] = (short)f2bf(a.y);
        r[2] = (short)f2bf(a.z); r[3] = (short)f2bf(a.w);
        r[4] = (short)f2bf(b.x); r[5] = (short)f2bf(b.y);
        r[6] = (short)f2bf(b.z); r[7] = (short)f2bf(b.w);
        return r;
    }
}

__global__ void prep_weights(const float* __restrict__ wd, const float* __restrict__ wu,
                             unsigned short* __restrict__ wd_bf,
                             unsigned short* __restrict__ wu_bf) {
    int i = (blockIdx.x * blockDim.x + threadIdx.x) * 4;   // 512 blocks * 256 thr * 4 = 524288
    float4 a = *(const float4*)(wd + i);
    ushort4 ua;
    ua.x = f2bf(a.x); ua.y = f2bf(a.y); ua.z = f2bf(a.z); ua.w = f2bf(a.w);
    *(ushort4*)(wd_bf + i) = ua;
    float4 b = *(const float4*)(wu + i);
    ushort4 ub;
    ub.x = f2bf(b.x); ub.y = f2bf(b.y); ub.z = f2bf(b.z); ub.w = f2bf(b.w);
    *(ushort4*)(wu_bf + i) = ub;
}

template<bool PREP>
__global__ __launch_bounds__(THREADS)
void gated_norm_kernel(const float* __restrict__ x,
                       const float* __restrict__ wd_f32,   // [R][DIM]
                       const float* __restrict__ wu_f32,   // [DIM][R]
                       const unsigned short* __restrict__ wd_bf,
                       const unsigned short* __restrict__ wu_bf,
                       float* __restrict__ out) {
    extern __shared__ char smem[];
    const int tid  = threadIdx.x;
    const int lane = tid & 63;
    const int wave = tid >> 6;      // 0..3
    const int l15  = lane & 15;
    const int lq   = lane >> 4;     // 0..3

    const long tok0 = (long)blockIdx.x * BT;
    const float* __restrict__ xblk = x + tok0 * DIMX;
    float* __restrict__ outblk = out + tok0 * DIMX;

    // staging mapping: thread -> (row = tid>>4, 16 threads per row)
    const int srow = tid >> 4;      // 0..15
    const int su   = tid & 15;      // 0..15

    float ss = 0.f;
    float4 v[8];

    // ---- prologue: load + stage chunk 0 (raw x as bf16, swizzled)
    {
        const float4* src = (const float4*)(xblk + (long)srow * DIMX);
        #pragma unroll
        for (int j = 0; j < 8; ++j) v[j] = src[su + 16 * j];
        #pragma unroll
        for (int j = 0; j < 8; ++j) {
            float4 f = v[j];
            ss += f.x * f.x + f.y * f.y + f.z * f.z + f.w * f.w;
            ushort4 u4;
            u4.x = f2bf(f.x); u4.y = f2bf(f.y); u4.z = f2bf(f.z); u4.w = f2bf(f.w);
            int col  = 4 * (su + 16 * j);
            int byte = (srow * 8192 + col * 2) ^ ((srow & 7) << 4);
            *(ushort4*)(smem + byte) = u4;
        }
    }
    __syncthreads();

    // ---- phase B: down-proj K-loop (pipelined: load c+1, MFMA c, stage c+1)
    f32x4 hacc[2] = {{0.f, 0.f, 0.f, 0.f}, {0.f, 0.f, 0.f, 0.f}};
    const int n0w = wave * 32;   // this wave covers r in [n0w, n0w+32)

    for (int c = 0; c < NCH; ++c) {
        if (c + 1 < NCH) {
            const float4* src = (const float4*)(xblk + (long)srow * DIMX + (c + 1) * KC);
            #pragma unroll
            for (int j = 0; j < 8; ++j) v[j] = src[su + 16 * j];
        }
        const int kbase = c * KC;
        #pragma unroll 4
        for (int ks = 0; ks < KC / 32; ++ks) {
            const int k0 = kbase + ks * 32;
            // A frag: x_lds[row=l15][k0 + 8*lq .. +8]
            const int abyte = (l15 * 8192 + (k0 + 8 * lq) * 2) ^ ((l15 & 7) << 4);
            bf16x8 a = *(const bf16x8*)(smem + abyte);
            #pragma unroll
            for (int nt = 0; nt < 2; ++nt) {
                const int r = n0w + nt * 16 + l15;
                bf16x8 b = load_w8<PREP>(wd_bf, wd_f32, (long)r * DIMX + k0 + 8 * lq);
                hacc[nt] = __builtin_amdgcn_mfma_f32_16x16x32_bf16(a, b, hacc[nt], 0, 0, 0);
            }
        }
        if (c + 1 < NCH) {
            #pragma unroll
            for (int j = 0; j < 8; ++j) {
                float4 f = v[j];
                ss += f.x * f.x + f.y * f.y + f.z * f.z + f.w * f.w;
                ushort4 u4;
                u4.x = f2bf(f.x); u4.y = f2bf(f.y); u4.z = f2bf(f.z); u4.w = f2bf(f.w);
                int col  = (c + 1) * KC + 4 * (su + 16 * j);
                int byte = (srow * 8192 + col * 2) ^ ((srow & 7) << 4);
                *(ushort4*)(smem + byte) = u4;
            }
        }
        __syncthreads();
    }

    // ---- inv_rms: reduce ss over the 16 threads of each row
    #pragma unroll
    for (int m = 1; m < 16; m <<= 1) ss += __shfl_xor(ss, m, 64);
    if (su == 0) {
        float invr = rsqrtf(ss * (1.0f / DIMX) + 1.1920929e-07f);
        *(float*)(smem + INV_OFF + srow * 4) = invr;
    }
    __syncthreads();

    // ---- scale h_pre by inv_rms, silu, write h to LDS as bf16
    #pragma unroll
    for (int nt = 0; nt < 2; ++nt) {
        const int r = n0w + nt * 16 + l15;
        #pragma unroll
        for (int i = 0; i < 4; ++i) {
            const int t = 4 * lq + i;                 // token (D-layout row)
            float invr = *(const float*)(smem + INV_OFF + t * 4);
            float hp = hacc[nt][i] * invr;
            float hs = hp * sigm(hp);                 // silu
            *(unsigned short*)(smem + H_OFF + (t * HP + r) * 2) = f2bf(hs);
        }
    }
    __syncthreads();

    // ---- phase C: up-proj (transposed: A = W_up tile, B = h^T), fused epilogue
    bf16x8 hb[4];
    #pragma unroll
    for (int ks = 0; ks < 4; ++ks)
        hb[ks] = *(const bf16x8*)(smem + H_OFF + (l15 * HP + ks * 32 + 8 * lq) * 2);
    const float invr_t = *(const float*)(smem + INV_OFF + l15 * 4);
    const int t = l15;                 // this lane's token in D layout (col)
    const int wbase = wave * (DIMX / 4);   // 1024 cols per wave

    for (int g = 0; g < 16; ++g) {
        const int d0 = wbase + g * 64;     // 4 tiles of 16 cols
        bf16x8 wa[4][4];
        #pragma unroll
        for (int tt = 0; tt < 4; ++tt) {
            const int drow = d0 + tt * 16 + l15;
            #pragma unroll
            for (int ks = 0; ks < 4; ++ks)
                wa[tt][ks] = load_w8<PREP>(wu_bf, wu_f32, (long)drow * RLOW + ks * 32 + 8 * lq);
        }
        f32x4 acc[4] = {{0.f,0.f,0.f,0.f},{0.f,0.f,0.f,0.f},{0.f,0.f,0.f,0.f},{0.f,0.f,0.f,0.f}};
        #pragma unroll
        for (int ks = 0; ks < 4; ++ks)
            #pragma unroll
            for (int tt = 0; tt < 4; ++tt)
                acc[tt] = __builtin_amdgcn_mfma_f32_16x16x32_bf16(wa[tt][ks], hb[ks], acc[tt], 0, 0, 0);

        #pragma unroll
        for (int tt = 0; tt < 4; ++tt) {
            const int dc = d0 + tt * 16 + 4 * lq;     // 4 consecutive d for token t
            const int xbyte = (t * 8192 + dc * 2) ^ ((t & 7) << 4);
            ushort4 xb = *(const ushort4*)(smem + xbyte);
            float4 o;
            o.x = bf2f(xb.x) * invr_t * sigm(acc[tt][0]);
            o.y = bf2f(xb.y) * invr_t * sigm(acc[tt][1]);
            o.z = bf2f(xb.z) * invr_t * sigm(acc[tt][2]);
            o.w = bf2f(xb.w) * invr_t * sigm(acc[tt][3]);
            *(float4*)(outblk + (long)t * DIMX + dc) = o;
        }
    }
}

extern "C" void kernel_launch(void* const* d_in, const int* in_sizes, int n_in,
                              void* d_out, int out_size, void* d_ws, size_t ws_size,
                              hipStream_t stream) {
    const float* x  = (const float*)d_in[0];
    const float* wd = (const float*)d_in[1];   // [128][4096]
    const float* wu = (const float*)d_in[2];   // [4096][128]
    float* out = (float*)d_out;

    const int ntok = in_sizes[0] / DIMX;       // 16384
    const int nblk = ntok / BT;                // 1024

    const size_t need = (size_t)2 * RLOW * DIMX * 2;   // 2 MB for bf16 weights
    if (ws_size >= need) {
        unsigned short* wd_bf = (unsigned short*)d_ws;
        unsigned short* wu_bf = wd_bf + (size_t)RLOW * DIMX;
        prep_weights<<<512, 256, 0, stream>>>(wd, wu, wd_bf, wu_bf);
        gated_norm_kernel<true><<<nblk, THREADS, LDS_BYTES, stream>>>(
            x, wd, wu, wd_bf, wu_bf, out);
    } else {
        gated_norm_kernel<false><<<nblk, THREADS, LDS_BYTES, stream>>>(
            x, wd, wu, nullptr, nullptr, out);
    }
}

// Round 2
// 342.727 us; speedup vs baseline: 1.2144x; 1.2144x over previous
//
#include <hip/hip_runtime.h>
#include <hip/hip_bf16.h>

// GatedNorm: out = xn * sigmoid(W_up @ silu(W_down @ xn)), xn = rmsnorm(x)
// B=4, S=4096, DIM=4096, R=128. All fp32 in/out.
//
// R1 redesign: occupancy over LDS residency.
//  - R0 kept x block-resident in 131 KB LDS -> 1 block/CU -> 1 wave/SIMD -> 12%
//    occupancy, 1 TB/s HBM. Latency-bound, not traffic-bound.
//  - Now: small double-buffered x-chunk staging (2 x [16][512] bf16 = 32 KB),
//    epilogue re-reads x from global (+256 MB traffic, but 4 blocks/CU overlap
//    all phases). LDS total 36.3 KB -> 4 blocks/CU, 16 waves/CU.

#define DIMX  4096
#define RLOW  128
#define BT    16
#define KC    512
#define NCH   (DIMX / KC)   // 8
#define THREADS 256

typedef __attribute__((ext_vector_type(8))) short  bf16x8;
typedef __attribute__((ext_vector_type(4))) float  f32x4;

// LDS layout (dynamic):
//   xbuf : 2 x [BT][KC] bf16 (double-buffered chunk), row stride 1024 B,
//          swizzle byte ^= ((row&7)<<4)
//   h_lds: [BT][HP] bf16 (HP=136 padded)
//   invr : [BT] float
#define XB_STRIDE 16384                    // bytes per chunk buffer (16*512*2)
#define H_OFF     (2 * XB_STRIDE)          // 32768
#define HP        136
#define INV_OFF   (H_OFF + BT * HP * 2)    // +4352
#define LDS_BYTES (INV_OFF + BT * 4)       // 37184 -> 4 blocks/CU

__device__ __forceinline__ unsigned short f2bf(float f) {
    unsigned int u = __float_as_uint(f);
    u = u + 0x7fffu + ((u >> 16) & 1u);     // RNE
    return (unsigned short)(u >> 16);
}
__device__ __forceinline__ float sigm(float v) { return 1.0f / (1.0f + __expf(-v)); }

template<bool PREP>
__device__ __forceinline__ bf16x8 load_w8(const unsigned short* __restrict__ wbf,
                                          const float* __restrict__ wf, long off) {
    if constexpr (PREP) {
        return *(const bf16x8*)(wbf + off);
    } else {
        float4 a = *(const float4*)(wf + off);
        float4 b = *(const float4*)(wf + off + 4);
        bf16x8 r;
        r[0] = (short)f2bf(a.x); r[1] = (short)f2bf(a.y);
        r[2] = (short)f2bf(a.z); r[3] = (short)f2bf(a.w);
        r[4] = (short)f2bf(b.x); r[5] = (short)f2bf(b.y);
        r[6] = (short)f2bf(b.z); r[7] = (short)f2bf(b.w);
        return r;
    }
}

__global__ void prep_weights(const float* __restrict__ wd, const float* __restrict__ wu,
                             unsigned short* __restrict__ wd_bf,
                             unsigned short* __restrict__ wu_bf) {
    int i = (blockIdx.x * blockDim.x + threadIdx.x) * 4;
    float4 a = *(const float4*)(wd + i);
    ushort4 ua;
    ua.x = f2bf(a.x); ua.y = f2bf(a.y); ua.z = f2bf(a.z); ua.w = f2bf(a.w);
    *(ushort4*)(wd_bf + i) = ua;
    float4 b = *(const float4*)(wu + i);
    ushort4 ub;
    ub.x = f2bf(b.x); ub.y = f2bf(b.y); ub.z = f2bf(b.z); ub.w = f2bf(b.w);
    *(ushort4*)(wu_bf + i) = ub;
}

template<bool PREP>
__global__ __launch_bounds__(THREADS)
void gated_norm_kernel(const float* __restrict__ x,
                       const float* __restrict__ wd_f32,   // [R][DIM]
                       const float* __restrict__ wu_f32,   // [DIM][R]
                       const unsigned short* __restrict__ wd_bf,
                       const unsigned short* __restrict__ wu_bf,
                       float* __restrict__ out) {
    extern __shared__ char smem[];
    const int tid  = threadIdx.x;
    const int lane = tid & 63;
    const int wave = tid >> 6;      // 0..3
    const int l15  = lane & 15;
    const int lq   = lane >> 4;     // 0..3

    const long tok0 = (long)blockIdx.x * BT;
    const float* __restrict__ xblk = x + tok0 * DIMX;
    float* __restrict__ outblk = out + tok0 * DIMX;

    // staging mapping: row = tid>>4, 16 threads per row
    const int srow = tid >> 4;      // 0..15 (token)
    const int su   = tid & 15;

    float ss = 0.f;
    float4 v[8];

    // ---- prologue: load + stage chunk 0 into buf 0
    {
        const float4* src = (const float4*)(xblk + (long)srow * DIMX);
        #pragma unroll
        for (int j = 0; j < 8; ++j) v[j] = src[su + 16 * j];
        #pragma unroll
        for (int j = 0; j < 8; ++j) {
            float4 f = v[j];
            ss += f.x * f.x + f.y * f.y + f.z * f.z + f.w * f.w;
            ushort4 u4;
            u4.x = f2bf(f.x); u4.y = f2bf(f.y); u4.z = f2bf(f.z); u4.w = f2bf(f.w);
            int byte = (srow * 1024 + 8 * (su + 16 * j)) ^ ((srow & 7) << 4);
            *(ushort4*)(smem + byte) = u4;
        }
    }
    __syncthreads();

    // ---- down-proj K-loop, double-buffered chunks
    f32x4 hacc[2] = {{0.f, 0.f, 0.f, 0.f}, {0.f, 0.f, 0.f, 0.f}};
    const int n0w = wave * 32;   // this wave covers r in [n0w, n0w+32)

    for (int c = 0; c < NCH; ++c) {
        if (c + 1 < NCH) {
            const float4* src = (const float4*)(xblk + (long)srow * DIMX + (c + 1) * KC);
            #pragma unroll
            for (int j = 0; j < 8; ++j) v[j] = src[su + 16 * j];
        }
        const char* xbuf = smem + (c & 1) * XB_STRIDE;
        #pragma unroll 4
        for (int ks = 0; ks < KC / 32; ++ks) {
            const int kk = ks * 32 + 8 * lq;          // chunk-local k
            const int abyte = (l15 * 1024 + kk * 2) ^ ((l15 & 7) << 4);
            bf16x8 a = *(const bf16x8*)(xbuf + abyte);
            const long kg = (long)c * KC + kk;        // global k
            #pragma unroll
            for (int nt = 0; nt < 2; ++nt) {
                const int r = n0w + nt * 16 + l15;
                bf16x8 b = load_w8<PREP>(wd_bf, wd_f32, (long)r * DIMX + kg);
                hacc[nt] = __builtin_amdgcn_mfma_f32_16x16x32_bf16(a, b, hacc[nt], 0, 0, 0);
            }
        }
        if (c + 1 < NCH) {
            char* nbuf = smem + ((c + 1) & 1) * XB_STRIDE;
            #pragma unroll
            for (int j = 0; j < 8; ++j) {
                float4 f = v[j];
                ss += f.x * f.x + f.y * f.y + f.z * f.z + f.w * f.w;
                ushort4 u4;
                u4.x = f2bf(f.x); u4.y = f2bf(f.y); u4.z = f2bf(f.z); u4.w = f2bf(f.w);
                int byte = (srow * 1024 + 8 * (su + 16 * j)) ^ ((srow & 7) << 4);
                *(ushort4*)(nbuf + byte) = u4;
            }
        }
        __syncthreads();
    }

    // ---- inv_rms: reduce ss over the 16 threads of each row
    #pragma unroll
    for (int m = 1; m < 16; m <<= 1) ss += __shfl_xor(ss, m, 64);
    if (su == 0) {
        float invr = rsqrtf(ss * (1.0f / DIMX) + 1.1920929e-07f);
        *(float*)(smem + INV_OFF + srow * 4) = invr;
    }
    __syncthreads();

    // ---- scale h_pre by inv_rms, silu, write h to LDS as bf16
    #pragma unroll
    for (int nt = 0; nt < 2; ++nt) {
        const int r = n0w + nt * 16 + l15;
        #pragma unroll
        for (int i = 0; i < 4; ++i) {
            const int t = 4 * lq + i;                 // token
            float invr = *(const float*)(smem + INV_OFF + t * 4);
            float hp = hacc[nt][i] * invr;
            float hs = hp * sigm(hp);                 // silu
            *(unsigned short*)(smem + H_OFF + (t * HP + r) * 2) = f2bf(hs);
        }
    }
    __syncthreads();

    // ---- up-proj (transposed: A = W_up tile, B = h^T), epilogue re-reads x
    bf16x8 hb[4];
    #pragma unroll
    for (int ks = 0; ks < 4; ++ks)
        hb[ks] = *(const bf16x8*)(smem + H_OFF + (l15 * HP + ks * 32 + 8 * lq) * 2);
    const float invr_t = *(const float*)(smem + INV_OFF + l15 * 4);
    const int t = l15;                     // this lane's token
    const int wbase = wave * (DIMX / 4);   // 1024 cols per wave

    for (int g = 0; g < 16; ++g) {
        const int d0 = wbase + g * 64;     // 4 tiles of 16 cols
        bf16x8 wa[4][4];
        #pragma unroll
        for (int tt = 0; tt < 4; ++tt) {
            const int drow = d0 + tt * 16 + l15;
            #pragma unroll
            for (int ks = 0; ks < 4; ++ks)
                wa[tt][ks] = load_w8<PREP>(wu_bf, wu_f32, (long)drow * RLOW + ks * 32 + 8 * lq);
        }
        f32x4 acc[4] = {{0.f,0.f,0.f,0.f},{0.f,0.f,0.f,0.f},{0.f,0.f,0.f,0.f},{0.f,0.f,0.f,0.f}};
        #pragma unroll
        for (int ks = 0; ks < 4; ++ks)
            #pragma unroll
            for (int tt = 0; tt < 4; ++tt)
                acc[tt] = __builtin_amdgcn_mfma_f32_16x16x32_bf16(wa[tt][ks], hb[ks], acc[tt], 0, 0, 0);

        #pragma unroll
        for (int tt = 0; tt < 4; ++tt) {
            const int dc = d0 + tt * 16 + 4 * lq;     // 4 consecutive d for token t
            float4 xf = *(const float4*)(xblk + (long)t * DIMX + dc);
            float4 o;
            o.x = xf.x * invr_t * sigm(acc[tt][0]);
            o.y = xf.y * invr_t * sigm(acc[tt][1]);
            o.z = xf.z * invr_t * sigm(acc[tt][2]);
            o.w = xf.w * invr_t * sigm(acc[tt][3]);
            *(float4*)(outblk + (long)t * DIMX + dc) = o;
        }
    }
}

extern "C" void kernel_launch(void* const* d_in, const int* in_sizes, int n_in,
                              void* d_out, int out_size, void* d_ws, size_t ws_size,
                              hipStream_t stream) {
    const float* x  = (const float*)d_in[0];
    const float* wd = (const float*)d_in[1];   // [128][4096]
    const float* wu = (const float*)d_in[2];   // [4096][128]
    float* out = (float*)d_out;

    const int ntok = in_sizes[0] / DIMX;       // 16384
    const int nblk = ntok / BT;                // 1024

    const size_t need = (size_t)2 * RLOW * DIMX * 2;   // 2 MB for bf16 weights
    if (ws_size >= need) {
        unsigned short* wd_bf = (unsigned short*)d_ws;
        unsigned short* wu_bf = wd_bf + (size_t)RLOW * DIMX;
        prep_weights<<<512, 256, 0, stream>>>(wd, wu, wd_bf, wu_bf);
        gated_norm_kernel<true><<<nblk, THREADS, LDS_BYTES, stream>>>(
            x, wd, wu, wd_bf, wu_bf, out);
    } else {
        gated_norm_kernel<false><<<nblk, THREADS, LDS_BYTES, stream>>>(
            x, wd, wu, nullptr, nullptr, out);
    }
}